// Round 4
// baseline (890.913 us; speedup 1.0000x reference)
//
#include <hip/hip_runtime.h>
#include <stdint.h>

typedef __bf16 bf16_t;
typedef __bf16 bf16x8 __attribute__((ext_vector_type(8)));
typedef float floatx4 __attribute__((ext_vector_type(4)));

#define N_ROWS 16384
#define D_IN   2048
#define D_OUT  2048
#define EPSF   1e-6f
#define TINYF  1e-15f

// async global->LDS, 16B/lane; LDS base wave-uniform, lane*16 implicit
__device__ __forceinline__ void load_lds16(const void* g, void* l) {
    __builtin_amdgcn_global_load_lds(
        (const __attribute__((address_space(1))) unsigned int*)(const unsigned int*)g,
        (__attribute__((address_space(3))) unsigned int*)(unsigned int*)l,
        16, 0, 0);
}

// ---------- Kernel 0: split W (f32) into bf16 hi/lo planes ----------
__global__ __launch_bounds__(256) void pvfc_wsplit(
    const float* __restrict__ W, bf16_t* __restrict__ Wh, bf16_t* __restrict__ Wl)
{
    const size_t i = ((size_t)blockIdx.x * 256 + threadIdx.x) * 8;
    float4 a = *(const float4*)(W + i);
    float4 c = *(const float4*)(W + i + 4);
    float v[8] = {a.x, a.y, a.z, a.w, c.x, c.y, c.z, c.w};
    bf16x8 hv, lv;
#pragma unroll
    for (int j = 0; j < 8; ++j) {
        const bf16_t h = (bf16_t)v[j];
        hv[j] = h;
        lv[j] = (bf16_t)(v[j] - (float)h);
    }
    *(bf16x8*)(Wh + i) = hv;
    *(bf16x8*)(Wl + i) = lv;
}

// ---------- Kernel 1: v = asinh(||x||)/||x|| * x, split into bf16 hi/lo ----------
// A layout: [rows][4096] bf16 : cols 0..2047 = v_hi, 2048..4095 = v_lo
__global__ __launch_bounds__(256) void pvfc_prologue(
    const float* __restrict__ x, bf16_t* __restrict__ Ap)
{
    __shared__ float red[4];
    const int row = blockIdx.x, tid = threadIdx.x;
    const int lane = tid & 63, wave = tid >> 6;

    const float* xr = x + (size_t)row * D_IN + tid * 8;
    float4 a = *(const float4*)xr;
    float4 c = *(const float4*)(xr + 4);
    float v[8] = {a.x, a.y, a.z, a.w, c.x, c.y, c.z, c.w};

    float s = 0.f;
#pragma unroll
    for (int i = 0; i < 8; ++i) s += v[i] * v[i];
#pragma unroll
    for (int off = 32; off > 0; off >>= 1) s += __shfl_down(s, off, 64);
    if (lane == 0) red[wave] = s;
    __syncthreads();
    const float s2  = red[0] + red[1] + red[2] + red[3];
    const float nrm = sqrtf(s2);
    const float coef = asinhf(nrm) / fmaxf(nrm, EPSF);

    bf16x8 hv, lv;
#pragma unroll
    for (int j = 0; j < 8; ++j) {
        const float vi = coef * v[j];
        const bf16_t h = (bf16_t)vi;
        hv[j] = h;
        lv[j] = (bf16_t)(vi - (float)h);
    }
    bf16_t* ar = Ap + (size_t)row * (2 * D_IN);
    *(bf16x8*)(ar + tid * 8)         = hv;
    *(bf16x8*)(ar + D_IN + tid * 8)  = lv;
}

// ---------- Kernel 2: U = Ah.Wh^T + Ah.Wl^T + Al.Wh^T  (96 k-tiles, plane-select) ----------
__global__ __launch_bounds__(256) void pvfc_gemm(
    const bf16_t* __restrict__ A,   // [rows][4096] hi|lo
    const bf16_t* __restrict__ Wh, const bf16_t* __restrict__ Wl, // [2048][2048] each
    float* __restrict__ U)          // [rows][2048] f32
{
    __shared__ __align__(16) bf16_t As[128 * 64];
    __shared__ __align__(16) bf16_t Bs[128 * 64];

    const int tid = threadIdx.x;
    const int wave = tid >> 6, lane = tid & 63;
    const int rowBase = blockIdx.y * 128, colBase = blockIdx.x * 128;
    const int laneRow = lane >> 3;          // 0..7
    const int laneCol = (lane & 7) * 8;     // bf16 elems in 64-wide K slice
    const int wm = wave >> 1, wn = wave & 1;
    const int m16 = lane & 15, quad = lane >> 4;

    floatx4 acc[4][4];
    const floatx4 zero = {0.f, 0.f, 0.f, 0.f};
#pragma unroll
    for (int mi = 0; mi < 4; ++mi)
#pragma unroll
        for (int ni = 0; ni < 4; ++ni) acc[mi][ni] = zero;

    for (int kt = 0; kt < 96; ++kt) {
        const int seg = kt >> 5;                 // 0:(Ah,Wh) 1:(Al,Wh) 2:(Ah,Wl)
        const int k0  = (kt & 31) * 64;
        const int aO  = (seg == 1) ? D_IN : 0;
        const bf16_t* Wp = (seg == 2) ? Wl : Wh;
        __syncthreads();
#pragma unroll
        for (int i = 0; i < 4; ++i) {
            const int c = i * 4 + wave;          // 8-row chunk 0..15
            load_lds16(A  + (size_t)(rowBase + c * 8 + laneRow) * (2 * D_IN) + aO + k0 + laneCol,
                       As + c * 512);
            load_lds16(Wp + (size_t)(colBase + c * 8 + laneRow) * D_IN + k0 + laneCol,
                       Bs + c * 512);
        }
        __syncthreads();
#pragma unroll
        for (int ks = 0; ks < 2; ++ks) {
            bf16x8 af[4], bfr[4];
#pragma unroll
            for (int mi = 0; mi < 4; ++mi)
                af[mi] = *(const bf16x8*)&As[(wm * 64 + mi * 16 + m16) * 64 + ks * 32 + quad * 8];
#pragma unroll
            for (int ni = 0; ni < 4; ++ni)
                bfr[ni] = *(const bf16x8*)&Bs[(wn * 64 + ni * 16 + m16) * 64 + ks * 32 + quad * 8];
#pragma unroll
            for (int mi = 0; mi < 4; ++mi)
#pragma unroll
                for (int ni = 0; ni < 4; ++ni)
                    acc[mi][ni] = __builtin_amdgcn_mfma_f32_16x16x32_bf16(
                        af[mi], bfr[ni], acc[mi][ni], 0, 0, 0);
        }
    }

    // C/D: col = lane&15 (N dim), row = quad*4 + reg (M dim)
#pragma unroll
    for (int mi = 0; mi < 4; ++mi)
#pragma unroll
        for (int ni = 0; ni < 4; ++ni) {
            const int col = colBase + wn * 64 + ni * 16 + m16;
            float* up = U + (size_t)(rowBase + wm * 64 + mi * 16 + quad * 4) * D_OUT + col;
#pragma unroll
            for (int r = 0; r < 4; ++r)
                up[(size_t)r * D_OUT] = acc[mi][ni][r];
        }
}

// ---------- Kernel 3: per-row hyperbolic chain, out = Ascale*u + alpha*b (f32) ----------
__global__ __launch_bounds__(256) void pvfc_epilogue(
    const float* __restrict__ U, const float* __restrict__ bvec,
    float* __restrict__ out)
{
    __shared__ float red[12];
    const int row = blockIdx.x, tid = threadIdx.x;
    const int lane = tid & 63, wave = tid >> 6;

    const float* ur = U + (size_t)row * D_OUT + tid * 8;
    float u[8];
    { float4 a = *(const float4*)ur, c = *(const float4*)(ur + 4);
      u[0]=a.x;u[1]=a.y;u[2]=a.z;u[3]=a.w;u[4]=c.x;u[5]=c.y;u[6]=c.z;u[7]=c.w; }
    float b[8];
    { const float* br = bvec + tid * 8;
      float4 a = *(const float4*)br, c = *(const float4*)(br + 4);
      b[0]=a.x;b[1]=a.y;b[2]=a.z;b[3]=a.w;b[4]=c.x;b[5]=c.y;b[6]=c.z;b[7]=c.w; }

    float su2 = 0.f, sub = 0.f, sbb = 0.f;
#pragma unroll
    for (int i = 0; i < 8; ++i) { su2 += u[i]*u[i]; sub += u[i]*b[i]; sbb += b[i]*b[i]; }
#pragma unroll
    for (int off = 32; off > 0; off >>= 1) {
        su2 += __shfl_down(su2, off, 64);
        sub += __shfl_down(sub, off, 64);
        sbb += __shfl_down(sbb, off, 64);
    }
    if (lane == 0) { red[wave] = su2; red[4 + wave] = sub; red[8 + wave] = sbb; }
    __syncthreads();
    su2 = red[0] + red[1] + red[2] + red[3];
    sub = red[4] + red[5] + red[6] + red[7];
    sbb = red[8] + red[9] + red[10] + red[11];

    // scalar chain (f32; verified against reference algebra; C=S=1)
    const float r0 = sqrtf(su2);
    const float t  = fminf(20.f / fmaxf(r0, EPSF), 1.f);    // proj_tan0
    const float rp = t * r0;
    const float coef_e = sinhf(rp) / fmaxf(rp, EPSF);       // exp0
    const float P  = coef_e * t;                            // y = P*u
    const float yn2 = P * P * su2;
    const float beta = 1.f / fmaxf(sqrtf(1.f + yn2), TINYF);
    const float c  = beta / (1.f + beta);                   // pt coef
    const float d  = P * sub;                               // <y,b>
    const float vn2   = sbb + c * d * d * (2.f + c * yn2);  // ||bt||^2
    const float dotxv = d * (1.f + c * yn2);                // <y,bt>
    const float g  = fmaxf(vn2 - dotxv * dotxv / (1.f + yn2), TINYF);
    const float rg = sqrtf(g);
    const float coef1 = beta / (1.f + beta);
    const float t1 = fmaxf(1.f + beta, TINYF);
    const float coef2 = -(beta * beta * beta) / (t1 * t1);
    const float lam = (1.f + beta) / fmaxf(beta, TINYF);
    const float z  = fminf(rg, 20.f);
    const float sc = (fabsf(z) < EPSF) ? (1.f + z * z * (1.f / 6.f))
                                       : (sinhf(z) / fmaxf(z, EPSF));
    const float L = lam * sc;
    const float alpha = L * coef1;                          // w = alpha*b + gamma*y
    const float gamma = L * (coef1 * c * d + coef2 * dotxv);
    const float wn2 = alpha * alpha * sbb + 2.f * alpha * gamma * d + gamma * gamma * yn2;
    const float bw  = 1.f / fmaxf(sqrtf(1.f + wn2), TINYF);
    const float xy  = alpha * d + gamma * yn2;
    const float coefg = coef1 * xy + (1.f - bw) / bw;       // gyro_add coef
    const float Ascale = P * (1.f + gamma + coefg);

    float* orow = out + (size_t)row * D_OUT + tid * 8;
    float4 o0, o1;
    o0.x = Ascale*u[0] + alpha*b[0]; o0.y = Ascale*u[1] + alpha*b[1];
    o0.z = Ascale*u[2] + alpha*b[2]; o0.w = Ascale*u[3] + alpha*b[3];
    o1.x = Ascale*u[4] + alpha*b[4]; o1.y = Ascale*u[5] + alpha*b[5];
    o1.z = Ascale*u[6] + alpha*b[6]; o1.w = Ascale*u[7] + alpha*b[7];
    *(float4*)orow       = o0;
    *(float4*)(orow + 4) = o1;
}

extern "C" void kernel_launch(void* const* d_in, const int* in_sizes, int n_in,
                              void* d_out, int out_size, void* d_ws, size_t ws_size,
                              hipStream_t stream)
{
    // Reference dtypes are float32 throughout (setup_inputs uses jnp.float32).
    const float* x = (const float*)d_in[0];
    const float* W = (const float*)d_in[1];
    const float* b = (const float*)d_in[2];
    float* out = (float*)d_out;

    // ws layout: Wh (8 MiB) | Wl (8 MiB) | per-chunk { A [chunk][4096] bf16 (8KB/row),
    //                                                  U [chunk][2048] f32  (8KB/row) }
    bf16_t* Wh = (bf16_t*)d_ws;
    bf16_t* Wl = Wh + (size_t)D_OUT * D_IN;
    char*   rest = (char*)(Wl + (size_t)D_OUT * D_IN);
    const size_t wbytes = (size_t)D_OUT * D_IN * 2 * 2;           // 16 MiB
    const size_t avail  = (ws_size > wbytes) ? ws_size - wbytes : 0;
    int chunk = (int)((avail / 16384 / 128) * 128);               // rows, multiple of 128
    if (chunk <= 0) chunk = 128;
    if (chunk > N_ROWS) chunk = N_ROWS;

    bf16_t* Ap = (bf16_t*)rest;
    float*  U  = (float*)(rest + (size_t)chunk * (2 * D_IN) * 2);

    pvfc_wsplit<<<(D_OUT * D_IN) / (256 * 8), 256, 0, stream>>>(W, Wh, Wl);
    for (int r0 = 0; r0 < N_ROWS; r0 += chunk) {
        const int rows = (N_ROWS - r0 < chunk) ? (N_ROWS - r0) : chunk;
        pvfc_prologue<<<rows, 256, 0, stream>>>(x + (size_t)r0 * D_IN, Ap);
        pvfc_gemm<<<dim3(D_OUT / 128, rows / 128), 256, 0, stream>>>(Ap, Wh, Wl, U);
        pvfc_epilogue<<<rows, 256, 0, stream>>>(U, b, out + (size_t)r0 * D_OUT);
    }
}

// Round 5
// 790.185 us; speedup vs baseline: 1.1275x; 1.1275x over previous
//
#include <hip/hip_runtime.h>
#include <stdint.h>

typedef __bf16 bf16_t;
typedef __bf16 bf16x8 __attribute__((ext_vector_type(8)));
typedef float floatx4 __attribute__((ext_vector_type(4)));

#define N_ROWS 16384
#define D_IN   2048
#define D_OUT  2048
#define EPSF   1e-6f
#define TINYF  1e-15f

// async global->LDS, 16B/lane; LDS base wave-uniform, lane*16 implicit
__device__ __forceinline__ void load_lds16(const void* g, void* l) {
    __builtin_amdgcn_global_load_lds(
        (const __attribute__((address_space(1))) unsigned int*)(const unsigned int*)g,
        (__attribute__((address_space(3))) unsigned int*)(unsigned int*)l,
        16, 0, 0);
}

// ---------- Kernel 0: split W (f32) into bf16 hi/lo planes ----------
__global__ __launch_bounds__(256) void pvfc_wsplit(
    const float* __restrict__ W, bf16_t* __restrict__ Wh, bf16_t* __restrict__ Wl)
{
    const size_t i = ((size_t)blockIdx.x * 256 + threadIdx.x) * 8;
    float4 a = *(const float4*)(W + i);
    float4 c = *(const float4*)(W + i + 4);
    float v[8] = {a.x, a.y, a.z, a.w, c.x, c.y, c.z, c.w};
    bf16x8 hv, lv;
#pragma unroll
    for (int j = 0; j < 8; ++j) {
        const bf16_t h = (bf16_t)v[j];
        hv[j] = h;
        lv[j] = (bf16_t)(v[j] - (float)h);
    }
    *(bf16x8*)(Wh + i) = hv;
    *(bf16x8*)(Wl + i) = lv;
}

// ---------- Kernel 1: v = asinh(||x||)/||x|| * x, split into bf16 hi/lo ----------
// A layout: [rows][4096] bf16 : cols 0..2047 = v_hi, 2048..4095 = v_lo
__global__ __launch_bounds__(256) void pvfc_prologue(
    const float* __restrict__ x, bf16_t* __restrict__ Ap)
{
    __shared__ float red[4];
    const int row = blockIdx.x, tid = threadIdx.x;
    const int lane = tid & 63, wave = tid >> 6;

    const float* xr = x + (size_t)row * D_IN + tid * 8;
    float4 a = *(const float4*)xr;
    float4 c = *(const float4*)(xr + 4);
    float v[8] = {a.x, a.y, a.z, a.w, c.x, c.y, c.z, c.w};

    float s = 0.f;
#pragma unroll
    for (int i = 0; i < 8; ++i) s += v[i] * v[i];
#pragma unroll
    for (int off = 32; off > 0; off >>= 1) s += __shfl_down(s, off, 64);
    if (lane == 0) red[wave] = s;
    __syncthreads();
    const float s2  = red[0] + red[1] + red[2] + red[3];
    const float nrm = sqrtf(s2);
    const float coef = asinhf(nrm) / fmaxf(nrm, EPSF);

    bf16x8 hv, lv;
#pragma unroll
    for (int j = 0; j < 8; ++j) {
        const float vi = coef * v[j];
        const bf16_t h = (bf16_t)vi;
        hv[j] = h;
        lv[j] = (bf16_t)(vi - (float)h);
    }
    bf16_t* ar = Ap + (size_t)row * (2 * D_IN);
    *(bf16x8*)(ar + tid * 8)         = hv;
    *(bf16x8*)(ar + D_IN + tid * 8)  = lv;
}

// ---------- Kernel 2: U = Ah.Wh^T + Ah.Wl^T + Al.Wh^T  (96 k-tiles) ----------
// LDS layout XOR-swizzled: logical 16B-chunk c of row r stored at chunk c^(r&7).
// Kills the 16-way ds_read_b128 bank conflict (row stride 128B = 32 banks).
__global__ __launch_bounds__(256) void pvfc_gemm(
    const bf16_t* __restrict__ A,   // [rows][4096] hi|lo
    const bf16_t* __restrict__ Wh, const bf16_t* __restrict__ Wl, // [2048][2048] each
    float* __restrict__ U)          // [rows][2048] f32
{
    __shared__ __align__(16) bf16_t As[128 * 64];
    __shared__ __align__(16) bf16_t Bs[128 * 64];

    const int tid = threadIdx.x;
    const int wave = tid >> 6, lane = tid & 63;
    const int rowBase = blockIdx.y * 128, colBase = blockIdx.x * 128;
    const int laneRow = lane >> 3;                          // 0..7
    const int laneCol = (((lane & 7) ^ (laneRow & 7)) * 8); // swizzled fetch chunk
    const int wm = wave >> 1, wn = wave & 1;
    const int m16 = lane & 15, quad = lane >> 4;
    const int sw  = m16 & 7;                                // read-side xor key

    floatx4 acc[4][4];
    const floatx4 zero = {0.f, 0.f, 0.f, 0.f};
#pragma unroll
    for (int mi = 0; mi < 4; ++mi)
#pragma unroll
        for (int ni = 0; ni < 4; ++ni) acc[mi][ni] = zero;

    for (int kt = 0; kt < 96; ++kt) {
        const int seg = kt >> 5;                 // 0:(Ah,Wh) 1:(Al,Wh) 2:(Ah,Wl)
        const int k0  = (kt & 31) * 64;
        const int aO  = (seg == 1) ? D_IN : 0;
        const bf16_t* Wp = (seg == 2) ? Wl : Wh;
        __syncthreads();
#pragma unroll
        for (int i = 0; i < 4; ++i) {
            const int c = i * 4 + wave;          // 8-row chunk 0..15 (wave-uniform)
            load_lds16(A  + (size_t)(rowBase + c * 8 + laneRow) * (2 * D_IN) + aO + k0 + laneCol,
                       As + c * 512);
            load_lds16(Wp + (size_t)(colBase + c * 8 + laneRow) * D_IN + k0 + laneCol,
                       Bs + c * 512);
        }
        __syncthreads();
#pragma unroll
        for (int ks = 0; ks < 2; ++ks) {
            bf16x8 af[4], bfr[4];
#pragma unroll
            for (int mi = 0; mi < 4; ++mi)
                af[mi] = *(const bf16x8*)&As[(wm * 64 + mi * 16 + m16) * 64
                                             + (((ks * 4 + quad) ^ sw) * 8)];
#pragma unroll
            for (int ni = 0; ni < 4; ++ni)
                bfr[ni] = *(const bf16x8*)&Bs[(wn * 64 + ni * 16 + m16) * 64
                                              + (((ks * 4 + quad) ^ sw) * 8)];
#pragma unroll
            for (int mi = 0; mi < 4; ++mi)
#pragma unroll
                for (int ni = 0; ni < 4; ++ni)
                    acc[mi][ni] = __builtin_amdgcn_mfma_f32_16x16x32_bf16(
                        af[mi], bfr[ni], acc[mi][ni], 0, 0, 0);
        }
    }

    // C/D: col = lane&15 (N dim), row = quad*4 + reg (M dim)
#pragma unroll
    for (int mi = 0; mi < 4; ++mi)
#pragma unroll
        for (int ni = 0; ni < 4; ++ni) {
            const int col = colBase + wn * 64 + ni * 16 + m16;
            float* up = U + (size_t)(rowBase + wm * 64 + mi * 16 + quad * 4) * D_OUT + col;
#pragma unroll
            for (int r = 0; r < 4; ++r)
                up[(size_t)r * D_OUT] = acc[mi][ni][r];
        }
}

// ---------- Kernel 3: per-row hyperbolic chain, out = Ascale*u + alpha*b (f32) ----------
__global__ __launch_bounds__(256) void pvfc_epilogue(
    const float* __restrict__ U, const float* __restrict__ bvec,
    float* __restrict__ out)
{
    __shared__ float red[12];
    const int row = blockIdx.x, tid = threadIdx.x;
    const int lane = tid & 63, wave = tid >> 6;

    const float* ur = U + (size_t)row * D_OUT + tid * 8;
    float u[8];
    { float4 a = *(const float4*)ur, c = *(const float4*)(ur + 4);
      u[0]=a.x;u[1]=a.y;u[2]=a.z;u[3]=a.w;u[4]=c.x;u[5]=c.y;u[6]=c.z;u[7]=c.w; }
    float b[8];
    { const float* br = bvec + tid * 8;
      float4 a = *(const float4*)br, c = *(const float4*)(br + 4);
      b[0]=a.x;b[1]=a.y;b[2]=a.z;b[3]=a.w;b[4]=c.x;b[5]=c.y;b[6]=c.z;b[7]=c.w; }

    float su2 = 0.f, sub = 0.f, sbb = 0.f;
#pragma unroll
    for (int i = 0; i < 8; ++i) { su2 += u[i]*u[i]; sub += u[i]*b[i]; sbb += b[i]*b[i]; }
#pragma unroll
    for (int off = 32; off > 0; off >>= 1) {
        su2 += __shfl_down(su2, off, 64);
        sub += __shfl_down(sub, off, 64);
        sbb += __shfl_down(sbb, off, 64);
    }
    if (lane == 0) { red[wave] = su2; red[4 + wave] = sub; red[8 + wave] = sbb; }
    __syncthreads();
    su2 = red[0] + red[1] + red[2] + red[3];
    sub = red[4] + red[5] + red[6] + red[7];
    sbb = red[8] + red[9] + red[10] + red[11];

    // scalar chain (f32; verified against reference algebra; C=S=1)
    const float r0 = sqrtf(su2);
    const float t  = fminf(20.f / fmaxf(r0, EPSF), 1.f);    // proj_tan0
    const float rp = t * r0;
    const float coef_e = sinhf(rp) / fmaxf(rp, EPSF);       // exp0
    const float P  = coef_e * t;                            // y = P*u
    const float yn2 = P * P * su2;
    const float beta = 1.f / fmaxf(sqrtf(1.f + yn2), TINYF);
    const float c  = beta / (1.f + beta);                   // pt coef
    const float d  = P * sub;                               // <y,b>
    const float vn2   = sbb + c * d * d * (2.f + c * yn2);  // ||bt||^2
    const float dotxv = d * (1.f + c * yn2);                // <y,bt>
    const float g  = fmaxf(vn2 - dotxv * dotxv / (1.f + yn2), TINYF);
    const float rg = sqrtf(g);
    const float coef1 = beta / (1.f + beta);
    const float t1 = fmaxf(1.f + beta, TINYF);
    const float coef2 = -(beta * beta * beta) / (t1 * t1);
    const float lam = (1.f + beta) / fmaxf(beta, TINYF);
    const float z  = fminf(rg, 20.f);
    const float sc = (fabsf(z) < EPSF) ? (1.f + z * z * (1.f / 6.f))
                                       : (sinhf(z) / fmaxf(z, EPSF));
    const float L = lam * sc;
    const float alpha = L * coef1;                          // w = alpha*b + gamma*y
    const float gamma = L * (coef1 * c * d + coef2 * dotxv);
    const float wn2 = alpha * alpha * sbb + 2.f * alpha * gamma * d + gamma * gamma * yn2;
    const float bw  = 1.f / fmaxf(sqrtf(1.f + wn2), TINYF);
    const float xy  = alpha * d + gamma * yn2;
    const float coefg = coef1 * xy + (1.f - bw) / bw;       // gyro_add coef
    const float Ascale = P * (1.f + gamma + coefg);

    float* orow = out + (size_t)row * D_OUT + tid * 8;
    float4 o0, o1;
    o0.x = Ascale*u[0] + alpha*b[0]; o0.y = Ascale*u[1] + alpha*b[1];
    o0.z = Ascale*u[2] + alpha*b[2]; o0.w = Ascale*u[3] + alpha*b[3];
    o1.x = Ascale*u[4] + alpha*b[4]; o1.y = Ascale*u[5] + alpha*b[5];
    o1.z = Ascale*u[6] + alpha*b[6]; o1.w = Ascale*u[7] + alpha*b[7];
    *(float4*)orow       = o0;
    *(float4*)(orow + 4) = o1;
}

extern "C" void kernel_launch(void* const* d_in, const int* in_sizes, int n_in,
                              void* d_out, int out_size, void* d_ws, size_t ws_size,
                              hipStream_t stream)
{
    // Reference dtypes are float32 throughout (setup_inputs uses jnp.float32).
    const float* x = (const float*)d_in[0];
    const float* W = (const float*)d_in[1];
    const float* b = (const float*)d_in[2];
    float* out = (float*)d_out;

    // ws layout: Wh (8 MiB) | Wl (8 MiB) | per-chunk { A [chunk][4096] bf16 (8KB/row),
    //                                                  U [chunk][2048] f32  (8KB/row) }
    bf16_t* Wh = (bf16_t*)d_ws;
    bf16_t* Wl = Wh + (size_t)D_OUT * D_IN;
    char*   rest = (char*)(Wl + (size_t)D_OUT * D_IN);
    const size_t wbytes = (size_t)D_OUT * D_IN * 2 * 2;           // 16 MiB
    const size_t avail  = (ws_size > wbytes) ? ws_size - wbytes : 0;
    int chunk = (int)((avail / 16384 / 128) * 128);               // rows, multiple of 128
    if (chunk <= 0) chunk = 128;
    if (chunk > N_ROWS) chunk = N_ROWS;

    bf16_t* Ap = (bf16_t*)rest;
    float*  U  = (float*)(rest + (size_t)chunk * (2 * D_IN) * 2);

    pvfc_wsplit<<<(D_OUT * D_IN) / (256 * 8), 256, 0, stream>>>(W, Wh, Wl);
    for (int r0 = 0; r0 < N_ROWS; r0 += chunk) {
        const int rows = (N_ROWS - r0 < chunk) ? (N_ROWS - r0) : chunk;
        pvfc_prologue<<<rows, 256, 0, stream>>>(x + (size_t)r0 * D_IN, Ap);
        pvfc_gemm<<<dim3(D_OUT / 128, rows / 128), 256, 0, stream>>>(Ap, Wh, Wl, U);
        pvfc_epilogue<<<rows, 256, 0, stream>>>(U, b, out + (size_t)r0 * D_OUT);
    }
}